// Round 9
// baseline (366.184 us; speedup 1.0000x reference)
//
#include <hip/hip_runtime.h>

// Transformer block on MI355X (gfx950).
// B=2, T=2048, C=1024, H=16, D=64. All GEMMs in bf16 MFMA (16x16x32).
// R1: acc array in scratch -> unroll + inline tanh.
// R2: attention latency-bound -> LDS-staged K/V, S^T/O^T register layouts.
// R3/R4: N=1024 GEMMs occupancy-bound -> BN=64 kernel (2 blocks/CU).
// R5: attention causal pairing (block j does q-tiles j and 31-j).
// R6: manual vmcnt NEUTRAL (compiler re-inserted vmcnt(0)).
// R7: asm-opaque ds_read_b128 + vmcnt(6) pipeline -> WIN.
// R8: pipeline ported to 128x128 (gemm_bt_p) for qkv/fc1 -> WIN.
// R9: fc2 was traffic-bound on BN=64 (FETCH 145MB vs 58MB unique; 8 MFMA
//     per 3 loads). fc2 -> gemm_bt_p<2> BN=128, grid(8,32)=1 block/CU
//     (pipeline carries latency; XCD j naturally owns n-tile j -> B L2-
//     resident, A streams L3 once). proj stays n64.

typedef unsigned short u16;
typedef unsigned int u32;
typedef __attribute__((ext_vector_type(8))) short v8s;   // 8 x bf16 (4 VGPR)
typedef __attribute__((ext_vector_type(4))) float v4f;   // MFMA acc

#define GAS __attribute__((address_space(1)))
#define LAS __attribute__((address_space(3)))

__device__ __forceinline__ u16 f2bf(float f) {
  u32 u = __float_as_uint(f);
  u = (u + 0x7FFF + ((u >> 16) & 1)) >> 16;  // RNE
  return (u16)u;
}
__device__ __forceinline__ float bf2f(u16 h) {
  return __uint_as_float(((u32)h) << 16);
}
__device__ __forceinline__ float fast_tanh(float x) {
  return 1.f - 2.f / (1.f + __expf(2.f * x));
}

// ---------------- weight transpose + fp32->bf16 convert ----------------
__global__ __launch_bounds__(256)
void wtrans(const float* __restrict__ W, u16* __restrict__ Wt, int K, int N) {
  __shared__ float tile[32][33];
  const int n0 = blockIdx.x << 5, k0 = blockIdx.y << 5;
  const int r = threadIdx.x >> 5, c = threadIdx.x & 31;
#pragma unroll
  for (int i = 0; i < 4; ++i)
    tile[r + 8 * i][c] = W[(size_t)(k0 + r + 8 * i) * N + n0 + c];
  __syncthreads();
#pragma unroll
  for (int i = 0; i < 4; ++i)
    Wt[(size_t)(n0 + r + 8 * i) * K + k0 + c] = f2bf(tile[c][r + 8 * i]);
}

// ---------------- LayerNorm (f32 in -> bf16 out), C=1024 ----------------
__global__ __launch_bounds__(256)
void ln_bf16(const float* __restrict__ x, const float* __restrict__ g,
             const float* __restrict__ be, u16* __restrict__ out) {
  constexpr int C = 1024;
  const int row = blockIdx.x, t = threadIdx.x;
  const float4 v = ((const float4*)(x + (size_t)row * C))[t];
  float s = v.x + v.y + v.z + v.w;
#pragma unroll
  for (int m = 32; m >= 1; m >>= 1) s += __shfl_xor(s, m);
  __shared__ float red[4], red2[4];
  if ((t & 63) == 0) red[t >> 6] = s;
  __syncthreads();
  const float mu = (red[0] + red[1] + red[2] + red[3]) * (1.f / C);
  const float dx = v.x - mu, dy = v.y - mu, dz = v.z - mu, dw = v.w - mu;
  float s2 = dx * dx + dy * dy + dz * dz + dw * dw;
#pragma unroll
  for (int m = 32; m >= 1; m >>= 1) s2 += __shfl_xor(s2, m);
  if ((t & 63) == 0) red2[t >> 6] = s2;
  __syncthreads();
  const float var = (red2[0] + red2[1] + red2[2] + red2[3]) * (1.f / C);
  const float rs = rsqrtf(var + 1e-5f);
  const int c = t << 2;
  u16 o0 = f2bf(dx * rs * g[c + 0] + be[c + 0]);
  u16 o1 = f2bf(dy * rs * g[c + 1] + be[c + 1]);
  u16 o2 = f2bf(dz * rs * g[c + 2] + be[c + 2]);
  u16 o3 = f2bf(dw * rs * g[c + 3] + be[c + 3]);
  uint2 pk;
  pk.x = (u32)o0 | ((u32)o1 << 16);
  pk.y = (u32)o2 | ((u32)o3 << 16);
  *(uint2*)(out + (size_t)row * C + c) = pk;
}

// ------- GEMM 128x128, depth-3 asm pipeline (qkv, fc1, fc2) --------------
template <int EPI>
__global__ __launch_bounds__(256)
void gemm_bt_p(const u16* __restrict__ A, const u16* __restrict__ Bt,
               const float* __restrict__ bias, const float* __restrict__ res,
               void* __restrict__ outp, int M, int N, int K) {
  __shared__ u16 As[4][128 * 32];
  __shared__ u16 Bs[4][128 * 32];
  const int tid = threadIdx.x;
  const int wave = tid >> 6, lane = tid & 63;
  const int m0 = blockIdx.y << 7, n0 = blockIdx.x << 7;

  v4f acc[4][4];
  const v4f vz = {0.f, 0.f, 0.f, 0.f};
#pragma unroll
  for (int i = 0; i < 4; ++i)
#pragma unroll
    for (int j = 0; j < 4; ++j) acc[i][j] = vz;

  const int wm = (wave >> 1) << 6, wn = (wave & 1) << 6;
  const int sr = lane >> 2;
  const int sc = (lane & 3) << 3;
  const int fr = lane & 15;
  const int fk = (lane >> 4) << 3;
  const int c0 = wave << 1;

  const u16* gA0 = A + (size_t)(m0 + c0 * 16 + sr) * K + sc;
  const u16* gA1 = A + (size_t)(m0 + c0 * 16 + 16 + sr) * K + sc;
  const u16* gB0 = Bt + (size_t)(n0 + c0 * 16 + sr) * K + sc;
  const u16* gB1 = Bt + (size_t)(n0 + c0 * 16 + 16 + sr) * K + sc;
  const int aoff = c0 * 512;  // elements within a buffer

  const u32 asb = (u32)(size_t)(LAS const u16*)&As[0][0];
  const u32 bsb = (u32)(size_t)(LAS const u16*)&Bs[0][0];
  const u32 afrag = (u32)(((wm + fr) << 6) + (fk << 1));  // bytes
  const u32 bfrag = (u32)(((wn + fr) << 6) + (fk << 1));

  const int nk = K >> 5;  // >= 4

#define P128_ISSUE(t, bf)                                                        \
  do {                                                                           \
    const int k0_ = (t) << 5;                                                    \
    __builtin_amdgcn_global_load_lds((GAS const u32*)(gA0 + k0_),                \
                                     (LAS u32*)(As[bf] + aoff), 16, 0, 0);       \
    __builtin_amdgcn_global_load_lds((GAS const u32*)(gA1 + k0_),                \
                                     (LAS u32*)(As[bf] + aoff + 512), 16, 0, 0); \
    __builtin_amdgcn_global_load_lds((GAS const u32*)(gB0 + k0_),                \
                                     (LAS u32*)(Bs[bf] + aoff), 16, 0, 0);       \
    __builtin_amdgcn_global_load_lds((GAS const u32*)(gB1 + k0_),                \
                                     (LAS u32*)(Bs[bf] + aoff + 512), 16, 0, 0); \
  } while (0)

  P128_ISSUE(0, 0);
  P128_ISSUE(1, 1);
  P128_ISSUE(2, 2);

  auto compute = [&](int kt) __attribute__((always_inline)) {
    const u32 ab = asb + ((u32)(kt & 3) << 13) + afrag;  // buf stride 8 KB
    const u32 bb = bsb + ((u32)(kt & 3) << 13) + bfrag;
    v8s a0, a1, a2, a3, b0, b1, b2, b3;
    asm volatile("ds_read_b128 %0, %1 offset:0"    : "=v"(a0) : "v"(ab));
    asm volatile("ds_read_b128 %0, %1 offset:1024" : "=v"(a1) : "v"(ab));
    asm volatile("ds_read_b128 %0, %1 offset:2048" : "=v"(a2) : "v"(ab));
    asm volatile("ds_read_b128 %0, %1 offset:3072" : "=v"(a3) : "v"(ab));
    asm volatile("ds_read_b128 %0, %1 offset:0"    : "=v"(b0) : "v"(bb));
    asm volatile("ds_read_b128 %0, %1 offset:1024" : "=v"(b1) : "v"(bb));
    asm volatile("ds_read_b128 %0, %1 offset:2048" : "=v"(b2) : "v"(bb));
    asm volatile("ds_read_b128 %0, %1 offset:3072" : "=v"(b3) : "v"(bb));
    asm volatile("s_waitcnt lgkmcnt(0)"
                 : "+v"(a0), "+v"(a1), "+v"(a2), "+v"(a3),
                   "+v"(b0), "+v"(b1), "+v"(b2), "+v"(b3)
                 :
                 : "memory");
    acc[0][0] = __builtin_amdgcn_mfma_f32_16x16x32_bf16(a0, b0, acc[0][0], 0, 0, 0);
    acc[0][1] = __builtin_amdgcn_mfma_f32_16x16x32_bf16(a0, b1, acc[0][1], 0, 0, 0);
    acc[0][2] = __builtin_amdgcn_mfma_f32_16x16x32_bf16(a0, b2, acc[0][2], 0, 0, 0);
    acc[0][3] = __builtin_amdgcn_mfma_f32_16x16x32_bf16(a0, b3, acc[0][3], 0, 0, 0);
    acc[1][0] = __builtin_amdgcn_mfma_f32_16x16x32_bf16(a1, b0, acc[1][0], 0, 0, 0);
    acc[1][1] = __builtin_amdgcn_mfma_f32_16x16x32_bf16(a1, b1, acc[1][1], 0, 0, 0);
    acc[1][2] = __builtin_amdgcn_mfma_f32_16x16x32_bf16(a1, b2, acc[1][2], 0, 0, 0);
    acc[1][3] = __builtin_amdgcn_mfma_f32_16x16x32_bf16(a1, b3, acc[1][3], 0, 0, 0);
    acc[2][0] = __builtin_amdgcn_mfma_f32_16x16x32_bf16(a2, b0, acc[2][0], 0, 0, 0);
    acc[2][1] = __builtin_amdgcn_mfma_f32_16x16x32_bf16(a2, b1, acc[2][1], 0, 0, 0);
    acc[2][2] = __builtin_amdgcn_mfma_f32_16x16x32_bf16(a2, b2, acc[2][2], 0, 0, 0);
    acc[2][3] = __builtin_amdgcn_mfma_f32_16x16x32_bf16(a2, b3, acc[2][3], 0, 0, 0);
    acc[3][0] = __builtin_amdgcn_mfma_f32_16x16x32_bf16(a3, b0, acc[3][0], 0, 0, 0);
    acc[3][1] = __builtin_amdgcn_mfma_f32_16x16x32_bf16(a3, b1, acc[3][1], 0, 0, 0);
    acc[3][2] = __builtin_amdgcn_mfma_f32_16x16x32_bf16(a3, b2, acc[3][2], 0, 0, 0);
    acc[3][3] = __builtin_amdgcn_mfma_f32_16x16x32_bf16(a3, b3, acc[3][3], 0, 0, 0);
  };

  for (int kt = 0; kt < nk - 3; ++kt) {
    asm volatile("s_waitcnt vmcnt(8)" ::: "memory");
    __builtin_amdgcn_s_barrier();
    P128_ISSUE(kt + 3, (kt + 3) & 3);
    compute(kt);
  }
  asm volatile("s_waitcnt vmcnt(8)" ::: "memory");
  __builtin_amdgcn_s_barrier();
  compute(nk - 3);
  asm volatile("s_waitcnt vmcnt(4)" ::: "memory");
  __builtin_amdgcn_s_barrier();
  compute(nk - 2);
  asm volatile("s_waitcnt vmcnt(0)" ::: "memory");
  __builtin_amdgcn_s_barrier();
  compute(nk - 1);
#undef P128_ISSUE

  const int er = (lane >> 4) << 2;
#pragma unroll
  for (int mi = 0; mi < 4; ++mi) {
#pragma unroll
    for (int ni = 0; ni < 4; ++ni) {
      const int col = n0 + wn + ni * 16 + fr;
      const float bcol = bias[col];
#pragma unroll
      for (int r = 0; r < 4; ++r) {
        const int row = m0 + wm + mi * 16 + er + r;
        float v = acc[mi][ni][r] + bcol;
        if constexpr (EPI == 1) {
          const float t = fast_tanh(0.7978845608028654f * (v + 0.044715f * v * v * v));
          v = 0.5f * v * (1.f + t);
        }
        if constexpr (EPI == 2) {
          v += res[(size_t)row * N + col];
          ((float*)outp)[(size_t)row * N + col] = v;
        } else {
          ((u16*)outp)[(size_t)row * N + col] = f2bf(v);
        }
      }
    }
  }
}

// ------- GEMM 128x64, depth-3 prefetch, asm ds_read (proj) ---------------
template <int EPI>
__global__ __launch_bounds__(256)
void gemm_bt_n64(const u16* __restrict__ A, const u16* __restrict__ Bt,
                 const float* __restrict__ bias, const float* __restrict__ res,
                 void* __restrict__ outp, int M, int N, int K) {
  __shared__ u16 As[4][128 * 32];
  __shared__ u16 Bs[4][64 * 32];
  const int tid = threadIdx.x;
  const int wave = tid >> 6, lane = tid & 63;
  const int m0 = blockIdx.y << 7, n0 = blockIdx.x << 6;

  v4f acc[4][2];
  const v4f vz = {0.f, 0.f, 0.f, 0.f};
#pragma unroll
  for (int i = 0; i < 4; ++i)
#pragma unroll
    for (int j = 0; j < 2; ++j) acc[i][j] = vz;

  const int wm = (wave >> 1) << 6, wn = (wave & 1) << 5;
  const int sr = lane >> 2;
  const int sc = (lane & 3) << 3;
  const int fr = lane & 15;
  const int fk = (lane >> 4) << 3;

  const u16* gA0 = A + (size_t)(m0 + wave * 32 + sr) * K + sc;
  const u16* gA1 = A + (size_t)(m0 + wave * 32 + 16 + sr) * K + sc;
  const u16* gB0 = Bt + (size_t)(n0 + wave * 16 + sr) * K + sc;
  const int aoff = wave * 1024;
  const int boff = wave * 512;

  const u32 asb = (u32)(size_t)(LAS const u16*)&As[0][0];
  const u32 bsb = (u32)(size_t)(LAS const u16*)&Bs[0][0];
  const u32 afrag = (u32)(((wm + fr) << 6) + (fk << 1));
  const u32 bfrag = (u32)(((wn + fr) << 6) + (fk << 1));

  const int nk = K >> 5;

#define N64_ISSUE(t, bf)                                                      \
  do {                                                                        \
    const int k0_ = (t) << 5;                                                 \
    __builtin_amdgcn_global_load_lds((GAS const u32*)(gA0 + k0_),             \
                                     (LAS u32*)(As[bf] + aoff), 16, 0, 0);    \
    __builtin_amdgcn_global_load_lds((GAS const u32*)(gA1 + k0_),             \
                                     (LAS u32*)(As[bf] + aoff + 512), 16, 0, 0); \
    __builtin_amdgcn_global_load_lds((GAS const u32*)(gB0 + k0_),             \
                                     (LAS u32*)(Bs[bf] + boff), 16, 0, 0);    \
  } while (0)

  N64_ISSUE(0, 0);
  N64_ISSUE(1, 1);
  N64_ISSUE(2, 2);

  auto compute = [&](int kt) __attribute__((always_inline)) {
    const u32 ab = asb + ((u32)(kt & 3) << 13) + afrag;  // A buf stride 8 KB
    const u32 bb = bsb + ((u32)(kt & 3) << 12) + bfrag;  // B buf stride 4 KB
    v8s a0, a1, a2, a3, b0, b1;
    asm volatile("ds_read_b128 %0, %1 offset:0"    : "=v"(a0) : "v"(ab));
    asm volatile("ds_read_b128 %0, %1 offset:1024" : "=v"(a1) : "v"(ab));
    asm volatile("ds_read_b128 %0, %1 offset:2048" : "=v"(a2) : "v"(ab));
    asm volatile("ds_read_b128 %0, %1 offset:3072" : "=v"(a3) : "v"(ab));
    asm volatile("ds_read_b128 %0, %1 offset:0"    : "=v"(b0) : "v"(bb));
    asm volatile("ds_read_b128 %0, %1 offset:1024" : "=v"(b1) : "v"(bb));
    asm volatile("s_waitcnt lgkmcnt(0)"
                 : "+v"(a0), "+v"(a1), "+v"(a2), "+v"(a3), "+v"(b0), "+v"(b1)
                 :
                 : "memory");
    acc[0][0] = __builtin_amdgcn_mfma_f32_16x16x32_bf16(a0, b0, acc[0][0], 0, 0, 0);
    acc[0][1] = __builtin_amdgcn_mfma_f32_16x16x32_bf16(a0, b1, acc[0][1], 0, 0, 0);
    acc[1][0] = __builtin_amdgcn_mfma_f32_16x16x32_bf16(a1, b0, acc[1][0], 0, 0, 0);
    acc[1][1] = __builtin_amdgcn_mfma_f32_16x16x32_bf16(a1, b1, acc[1][1], 0, 0, 0);
    acc[2][0] = __builtin_amdgcn_mfma_f32_16x16x32_bf16(a2, b0, acc[2][0], 0, 0, 0);
    acc[2][1] = __builtin_amdgcn_mfma_f32_16x16x32_bf16(a2, b1, acc[2][1], 0, 0, 0);
    acc[3][0] = __builtin_amdgcn_mfma_f32_16x16x32_bf16(a3, b0, acc[3][0], 0, 0, 0);
    acc[3][1] = __builtin_amdgcn_mfma_f32_16x16x32_bf16(a3, b1, acc[3][1], 0, 0, 0);
  };

  for (int kt = 0; kt < nk - 2; ++kt) {
    asm volatile("s_waitcnt vmcnt(6)" ::: "memory");
    __builtin_amdgcn_s_barrier();
    if (kt + 3 < nk) N64_ISSUE(kt + 3, (kt + 3) & 3);
    compute(kt);
  }
  asm volatile("s_waitcnt vmcnt(3)" ::: "memory");
  __builtin_amdgcn_s_barrier();
  compute(nk - 2);
  asm volatile("s_waitcnt vmcnt(0)" ::: "memory");
  __builtin_amdgcn_s_barrier();
  compute(nk - 1);
#undef N64_ISSUE

  const int er = (lane >> 4) << 2;
#pragma unroll
  for (int mi = 0; mi < 4; ++mi) {
#pragma unroll
    for (int ni = 0; ni < 2; ++ni) {
      const int col = n0 + wn + ni * 16 + fr;
      const float bcol = bias[col];
#pragma unroll
      for (int r = 0; r < 4; ++r) {
        const int row = m0 + wm + mi * 16 + er + r;
        float v = acc[mi][ni][r] + bcol;
        if constexpr (EPI == 1) {
          const float t = fast_tanh(0.7978845608028654f * (v + 0.044715f * v * v * v));
          v = 0.5f * v * (1.f + t);
        }
        if constexpr (EPI == 2) {
          v += res[(size_t)row * N + col];
          ((float*)outp)[(size_t)row * N + col] = v;
        } else {
          ((u16*)outp)[(size_t)row * N + col] = f2bf(v);
        }
      }
    }
  }
}

// ---------------- V -> Vt [B,H,D,T] bf16 (transpose via LDS) -------------
__global__ __launch_bounds__(256)
void transpose_v(const u16* __restrict__ qkv, u16* __restrict__ Vt) {
  __shared__ u16 tile[64][65];
  const int t0 = blockIdx.x << 6;
  const int bh = blockIdx.y;
  const int b = bh >> 4, h = bh & 15;
  const int r4 = threadIdx.x >> 6, c = threadIdx.x & 63;
#pragma unroll
  for (int i = 0; i < 16; ++i) {
    const int r = r4 * 16 + i;
    tile[r][c] = qkv[(size_t)(b * 2048 + t0 + r) * 3072 + 2048 + h * 64 + c];
  }
  __syncthreads();
#pragma unroll
  for (int i = 0; i < 16; ++i) {
    const int d = r4 * 16 + i;
    Vt[(size_t)bh * 64 * 2048 + (size_t)d * 2048 + t0 + c] = tile[c][d];
  }
}

// ---------------- flash attention (causal, balanced pairing) -------------
constexpr int PSTR = 88;  // P row stride (u16): 176B = 16B-mult, 2-way banks

template <bool MASKED>
__device__ __forceinline__ void attn_sub(
    const v8s (&kf)[4][2], const v8s (&vfr)[4][2], const v8s (&qf)[2],
    v4f (&ot)[4], float& m_i, float& l_i, u16* __restrict__ pw,
    const int kb, const int qrow, const int fr, const int fg) {
  const v4f vz = {0.f, 0.f, 0.f, 0.f};
  v4f st[4];
#pragma unroll
  for (int ks = 0; ks < 4; ++ks) {
    st[ks] = vz;
    st[ks] = __builtin_amdgcn_mfma_f32_16x16x32_bf16(kf[ks][0], qf[0], st[ks], 0, 0, 0);
    st[ks] = __builtin_amdgcn_mfma_f32_16x16x32_bf16(kf[ks][1], qf[1], st[ks], 0, 0, 0);
  }
  const int q = qrow + fr;
  float e[4][4];
  float mt = -1e30f;
#pragma unroll
  for (int ks = 0; ks < 4; ++ks)
#pragma unroll
    for (int r = 0; r < 4; ++r) {
      float v = st[ks][r] * 0.125f;  // fold 1/sqrt(64)
      if (MASKED) v = (kb + ks * 16 + fg * 4 + r <= q) ? v : -1e30f;
      e[ks][r] = v;
      mt = fmaxf(mt, v);
    }
  mt = fmaxf(mt, __shfl_xor(mt, 16));
  mt = fmaxf(mt, __shfl_xor(mt, 32));
  const float m_new = fmaxf(m_i, mt);
  const float alpha = __expf(m_i - m_new);
  m_i = m_new;
  float ls = 0.f;
#pragma unroll
  for (int ks = 0; ks < 4; ++ks)
#pragma unroll
    for (int r = 0; r < 4; ++r) {
      e[ks][r] = __expf(e[ks][r] - m_new);
      ls += e[ks][r];
    }
  ls += __shfl_xor(ls, 16);
  ls += __shfl_xor(ls, 32);
  l_i = l_i * alpha + ls;
#pragma unroll
  for (int ds = 0; ds < 4; ++ds) ot[ds] *= alpha;
#pragma unroll
  for (int ks = 0; ks < 4; ++ks) {
    ushort4 pk4;
    pk4.x = f2bf(e[ks][0]);
    pk4.y = f2bf(e[ks][1]);
    pk4.z = f2bf(e[ks][2]);
    pk4.w = f2bf(e[ks][3]);
    *(ushort4*)&pw[fr * PSTR + ks * 16 + fg * 4] = pk4;
  }
  const v8s pf0 = *(const v8s*)&pw[fr * PSTR + fg * 8];
  const v8s pf1 = *(const v8s*)&pw[fr * PSTR + 32 + fg * 8];
#pragma unroll
  for (int ds = 0; ds < 4; ++ds) {
    ot[ds] = __builtin_amdgcn_mfma_f32_16x16x32_bf16(vfr[ds][0], pf0, ot[ds], 0, 0, 0);
    ot[ds] = __builtin_amdgcn_mfma_f32_16x16x32_bf16(vfr[ds][1], pf1, ot[ds], 0, 0, 0);
  }
}

__global__ __launch_bounds__(256)
void attn_kernel(const u16* __restrict__ qkv, const u16* __restrict__ Vt,
                 u16* __restrict__ y) {
  constexpr int T = 2048, D = 64, C = 1024, QS = 3072;
  __shared__ alignas(16) u16 Ktile[2][64 * 64];
  __shared__ alignas(16) u16 Vtile[2][64 * 64];
  __shared__ alignas(16) u16 Pw[4][16 * PSTR];

  const int tid = threadIdx.x, wave = tid >> 6, lane = tid & 63;
  const int fr = lane & 15, fg = lane >> 4;
  const int bh = blockIdx.y, b = bh >> 4, h = bh & 15;
  const int ta = blockIdx.x, tb = 31 - ta;
  const u16* qkvb = qkv + (size_t)b * T * QS + h * 64;  // Q base
  const u16* Kg = qkvb + 1024;                          // K base
  const u16* Vh = Vt + (size_t)bh * D * T;
  u16* pw = &Pw[wave][0];

  const int rowA = ta * 64 + wave * 16;
  const int rowB = tb * 64 + wave * 16;

  v8s qfA[2], qfB[2];
#pragma unroll
  for (int dh = 0; dh < 2; ++dh) {
    qfA[dh] = *(const v8s*)&qkvb[(size_t)(rowA + fr) * QS + dh * 32 + fg * 8];
    qfB[dh] = *(const v8s*)&qkvb[(size_t)(rowB + fr) * QS + dh * 32 + fg * 8];
  }

  const v4f vz = {0.f, 0.f, 0.f, 0.f};
  v4f otA[4], otB[4];
#pragma unroll
  for (int ds = 0; ds < 4; ++ds) { otA[ds] = vz; otB[ds] = vz; }
  float mA = -1e30f, lA = 0.f, mB = -1e30f, lB = 0.f;

  const int srow = lane >> 3;
  const int sg0 = lane & 7;

  const int nt = tb + 1;
  {
#pragma unroll
    for (int cc = 0; cc < 2; ++cc) {
      const int r0 = wave * 16 + cc * 8;
      const int rr = r0 + srow;
      const int gg = sg0 ^ (rr & 7);
      __builtin_amdgcn_global_load_lds(
          (GAS const u32*)(Kg + (size_t)rr * QS + gg * 8),
          (LAS u32*)(Ktile[0] + r0 * 64), 16, 0, 0);
      __builtin_amdgcn_global_load_lds(
          (GAS const u32*)(Vh + (size_t)rr * T + gg * 8),
          (LAS u32*)(Vtile[0] + r0 * 64), 16, 0, 0);
    }
  }
  for (int kt = 0; kt < nt; ++kt) {
    __syncthreads();
    if (kt + 1 < nt) {
      const int kb1 = (kt + 1) << 6;
      const int nb = (kt + 1) & 1;
#pragma unroll
      for (int cc = 0; cc < 2; ++cc) {
        const int r0 = wave * 16 + cc * 8;
        const int rr = r0 + srow;
        const int gg = sg0 ^ (rr & 7);
        __builtin_amdgcn_global_load_lds(
            (GAS const u32*)(Kg + (size_t)(kb1 + rr) * QS + gg * 8),
            (LAS u32*)(Ktile[nb] + r0 * 64), 16, 0, 0);
        __builtin_amdgcn_global_load_lds(
            (GAS const u32*)(Vh + (size_t)rr * T + kb1 + gg * 8),
            (LAS u32*)(Vtile[nb] + r0 * 64), 16, 0, 0);
      }
    }
    const u16* Kt = Ktile[kt & 1];
    const u16* Vi = Vtile[kt & 1];
    const int kb = kt << 6;
    const int swz = fr & 7;
    v8s kf[4][2], vfr[4][2];
#pragma unroll
    for (int ks = 0; ks < 4; ++ks) {
      const int rr = ks * 16 + fr;
      kf[ks][0] = *(const v8s*)&Kt[rr * 64 + ((0 + fg) ^ swz) * 8];
      kf[ks][1] = *(const v8s*)&Kt[rr * 64 + ((4 + fg) ^ swz) * 8];
      vfr[ks][0] = *(const v8s*)&Vi[rr * 64 + ((0 + fg) ^ swz) * 8];
      vfr[ks][1] = *(const v8s*)&Vi[rr * 64 + ((4 + fg) ^ swz) * 8];
    }
    if (kt < ta) {
      attn_sub<false>(kf, vfr, qfA, otA, mA, lA, pw, kb, rowA, fr, fg);
      attn_sub<false>(kf, vfr, qfB, otB, mB, lB, pw, kb, rowB, fr, fg);
    } else if (kt == ta) {
      attn_sub<true>(kf, vfr, qfA, otA, mA, lA, pw, kb, rowA, fr, fg);
      attn_sub<false>(kf, vfr, qfB, otB, mB, lB, pw, kb, rowB, fr, fg);
    } else if (kt < tb) {
      attn_sub<false>(kf, vfr, qfB, otB, mB, lB, pw, kb, rowB, fr, fg);
    } else {
      attn_sub<true>(kf, vfr, qfB, otB, mB, lB, pw, kb, rowB, fr, fg);
    }
  }

  const float invA = 1.f / lA, invB = 1.f / lB;
#pragma unroll
  for (int ds = 0; ds < 4; ++ds) {
    ushort4 a4, b4;
    a4.x = f2bf(otA[ds][0] * invA);
    a4.y = f2bf(otA[ds][1] * invA);
    a4.z = f2bf(otA[ds][2] * invA);
    a4.w = f2bf(otA[ds][3] * invA);
    b4.x = f2bf(otB[ds][0] * invB);
    b4.y = f2bf(otB[ds][1] * invB);
    b4.z = f2bf(otB[ds][2] * invB);
    b4.w = f2bf(otB[ds][3] * invB);
    *(ushort4*)&y[(size_t)(b * T + rowA + fr) * C + h * D + ds * 16 + fg * 4] = a4;
    *(ushort4*)&y[(size_t)(b * T + rowB + fr) * C + h * D + ds * 16 + fg * 4] = b4;
  }
}

// ------------------------------- launch ----------------------------------
extern "C" void kernel_launch(void* const* d_in, const int* in_sizes, int n_in,
                              void* d_out, int out_size, void* d_ws, size_t ws_size,
                              hipStream_t stream) {
  const float* x      = (const float*)d_in[0];
  const float* ln1_g  = (const float*)d_in[1];
  const float* ln1_b  = (const float*)d_in[2];
  const float* W_attn = (const float*)d_in[3];
  const float* b_attn = (const float*)d_in[4];
  const float* W_o    = (const float*)d_in[5];
  const float* b_o    = (const float*)d_in[6];
  const float* ln2_g  = (const float*)d_in[7];
  const float* ln2_b  = (const float*)d_in[8];
  const float* W_fc   = (const float*)d_in[9];
  const float* b_fc   = (const float*)d_in[10];
  const float* W_fc2  = (const float*)d_in[11];
  const float* b_fc2  = (const float*)d_in[12];
  float* out = (float*)d_out;
  char* ws = (char*)d_ws;

  const size_t MB = 1u << 20;
  u16* Wattn_t = (u16*)(ws + 0 * MB);   // 6MB
  u16* Wo_t    = (u16*)(ws + 6 * MB);   // 2MB
  u16* Wfc_t   = (u16*)(ws + 8 * MB);   // 8MB
  u16* Wfc2_t  = (u16*)(ws + 16 * MB);  // 8MB
  float* x1    = (float*)(ws + 24 * MB); // 16MB
  u16* h1      = (u16*)(ws + 40 * MB);  // 8MB
  u16* qkv     = (u16*)(ws + 48 * MB);  // 24MB (alive through attn)
  u16* Vt      = (u16*)(ws + 88 * MB);  // 8MB
  u16* yb      = (u16*)(ws + 40 * MB);  // reuse h1 (dead after qkv GEMM)
  u16* h2      = (u16*)(ws + 48 * MB);  // reuse qkv (dead after attn)
  u16* ab      = (u16*)(ws + 56 * MB);  // 32MB (56..88)

  wtrans<<<dim3(3072 / 32, 1024 / 32), 256, 0, stream>>>(W_attn, Wattn_t, 1024, 3072);
  wtrans<<<dim3(1024 / 32, 1024 / 32), 256, 0, stream>>>(W_o, Wo_t, 1024, 1024);
  wtrans<<<dim3(4096 / 32, 1024 / 32), 256, 0, stream>>>(W_fc, Wfc_t, 1024, 4096);
  wtrans<<<dim3(1024 / 32, 4096 / 32), 256, 0, stream>>>(W_fc2, Wfc2_t, 4096, 1024);

  ln_bf16<<<4096, 256, 0, stream>>>(x, ln1_g, ln1_b, h1);
  gemm_bt_p<0><<<dim3(3072 / 128, 4096 / 128), 256, 0, stream>>>(
      h1, Wattn_t, b_attn, nullptr, qkv, 4096, 3072, 1024);
  transpose_v<<<dim3(2048 / 64, 32), 256, 0, stream>>>(qkv, Vt);
  attn_kernel<<<dim3(16, 32), 256, 0, stream>>>(qkv, Vt, yb);
  gemm_bt_n64<2><<<dim3(1024 / 64, 4096 / 128), 256, 0, stream>>>(
      yb, Wo_t, b_o, x, x1, 4096, 1024, 1024);
  ln_bf16<<<4096, 256, 0, stream>>>(x1, ln2_g, ln2_b, h2);
  gemm_bt_p<1><<<dim3(4096 / 128, 4096 / 128), 256, 0, stream>>>(
      h2, Wfc_t, b_fc, nullptr, ab, 4096, 4096, 1024);
  gemm_bt_p<2><<<dim3(1024 / 128, 4096 / 128), 256, 0, stream>>>(
      ab, Wfc2_t, b_fc2, x1, out, 4096, 1024, 4096);
}

// Round 10
// 364.455 us; speedup vs baseline: 1.0047x; 1.0047x over previous
//
#include <hip/hip_runtime.h>

// Transformer block on MI355X (gfx950).
// B=2, T=2048, C=1024, H=16, D=64. All GEMMs in bf16 MFMA (16x16x32).
// R1: acc array in scratch -> unroll + inline tanh.
// R2: attention latency-bound -> LDS-staged K/V, S^T/O^T register layouts.
// R3/R4: N=1024 GEMMs occupancy-bound -> BN=64 kernel (2 blocks/CU).
// R5: attention causal pairing (block j does q-tiles j and 31-j).
// R6: manual vmcnt NEUTRAL (compiler re-inserted vmcnt(0)).
// R7: asm-opaque ds_read_b128 + vmcnt(6) pipeline -> WIN.
// R8: pipeline ported to 128x128 (gemm_bt_p) for qkv/fc1 -> WIN.
// R9: fc2 on p128 NEUTRAL; FETCH unchanged (XCD-L2 theory wrong). Counters
//     show 1256 cy/iter vs ~170 cy HBM share -> latency-bound, depth-3 lead
//     (~600-900cy) marginal vs ~900cy HBM latency at 1 block/CU.
// R10: gemm_bt_p6 for fc2: 6 LDS buffers (96KB, 1 block/CU) depth-5
//      prefetch, steady-state vmcnt(16) -> lead ~5 compute phases.

typedef unsigned short u16;
typedef unsigned int u32;
typedef __attribute__((ext_vector_type(8))) short v8s;   // 8 x bf16 (4 VGPR)
typedef __attribute__((ext_vector_type(4))) float v4f;   // MFMA acc

#define GAS __attribute__((address_space(1)))
#define LAS __attribute__((address_space(3)))

__device__ __forceinline__ u16 f2bf(float f) {
  u32 u = __float_as_uint(f);
  u = (u + 0x7FFF + ((u >> 16) & 1)) >> 16;  // RNE
  return (u16)u;
}
__device__ __forceinline__ float bf2f(u16 h) {
  return __uint_as_float(((u32)h) << 16);
}
__device__ __forceinline__ float fast_tanh(float x) {
  return 1.f - 2.f / (1.f + __expf(2.f * x));
}

// ---------------- weight transpose + fp32->bf16 convert ----------------
__global__ __launch_bounds__(256)
void wtrans(const float* __restrict__ W, u16* __restrict__ Wt, int K, int N) {
  __shared__ float tile[32][33];
  const int n0 = blockIdx.x << 5, k0 = blockIdx.y << 5;
  const int r = threadIdx.x >> 5, c = threadIdx.x & 31;
#pragma unroll
  for (int i = 0; i < 4; ++i)
    tile[r + 8 * i][c] = W[(size_t)(k0 + r + 8 * i) * N + n0 + c];
  __syncthreads();
#pragma unroll
  for (int i = 0; i < 4; ++i)
    Wt[(size_t)(n0 + r + 8 * i) * K + k0 + c] = f2bf(tile[c][r + 8 * i]);
}

// ---------------- LayerNorm (f32 in -> bf16 out), C=1024 ----------------
__global__ __launch_bounds__(256)
void ln_bf16(const float* __restrict__ x, const float* __restrict__ g,
             const float* __restrict__ be, u16* __restrict__ out) {
  constexpr int C = 1024;
  const int row = blockIdx.x, t = threadIdx.x;
  const float4 v = ((const float4*)(x + (size_t)row * C))[t];
  float s = v.x + v.y + v.z + v.w;
#pragma unroll
  for (int m = 32; m >= 1; m >>= 1) s += __shfl_xor(s, m);
  __shared__ float red[4], red2[4];
  if ((t & 63) == 0) red[t >> 6] = s;
  __syncthreads();
  const float mu = (red[0] + red[1] + red[2] + red[3]) * (1.f / C);
  const float dx = v.x - mu, dy = v.y - mu, dz = v.z - mu, dw = v.w - mu;
  float s2 = dx * dx + dy * dy + dz * dz + dw * dw;
#pragma unroll
  for (int m = 32; m >= 1; m >>= 1) s2 += __shfl_xor(s2, m);
  if ((t & 63) == 0) red2[t >> 6] = s2;
  __syncthreads();
  const float var = (red2[0] + red2[1] + red2[2] + red2[3]) * (1.f / C);
  const float rs = rsqrtf(var + 1e-5f);
  const int c = t << 2;
  u16 o0 = f2bf(dx * rs * g[c + 0] + be[c + 0]);
  u16 o1 = f2bf(dy * rs * g[c + 1] + be[c + 1]);
  u16 o2 = f2bf(dz * rs * g[c + 2] + be[c + 2]);
  u16 o3 = f2bf(dw * rs * g[c + 3] + be[c + 3]);
  uint2 pk;
  pk.x = (u32)o0 | ((u32)o1 << 16);
  pk.y = (u32)o2 | ((u32)o3 << 16);
  *(uint2*)(out + (size_t)row * C + c) = pk;
}

// ------- GEMM 128x128, depth-3 asm pipeline (qkv, fc1) -------------------
template <int EPI>
__global__ __launch_bounds__(256)
void gemm_bt_p(const u16* __restrict__ A, const u16* __restrict__ Bt,
               const float* __restrict__ bias, const float* __restrict__ res,
               void* __restrict__ outp, int M, int N, int K) {
  __shared__ u16 As[4][128 * 32];
  __shared__ u16 Bs[4][128 * 32];
  const int tid = threadIdx.x;
  const int wave = tid >> 6, lane = tid & 63;
  const int m0 = blockIdx.y << 7, n0 = blockIdx.x << 7;

  v4f acc[4][4];
  const v4f vz = {0.f, 0.f, 0.f, 0.f};
#pragma unroll
  for (int i = 0; i < 4; ++i)
#pragma unroll
    for (int j = 0; j < 4; ++j) acc[i][j] = vz;

  const int wm = (wave >> 1) << 6, wn = (wave & 1) << 6;
  const int sr = lane >> 2;
  const int sc = (lane & 3) << 3;
  const int fr = lane & 15;
  const int fk = (lane >> 4) << 3;
  const int c0 = wave << 1;

  const u16* gA0 = A + (size_t)(m0 + c0 * 16 + sr) * K + sc;
  const u16* gA1 = A + (size_t)(m0 + c0 * 16 + 16 + sr) * K + sc;
  const u16* gB0 = Bt + (size_t)(n0 + c0 * 16 + sr) * K + sc;
  const u16* gB1 = Bt + (size_t)(n0 + c0 * 16 + 16 + sr) * K + sc;
  const int aoff = c0 * 512;  // elements within a buffer

  const u32 asb = (u32)(size_t)(LAS const u16*)&As[0][0];
  const u32 bsb = (u32)(size_t)(LAS const u16*)&Bs[0][0];
  const u32 afrag = (u32)(((wm + fr) << 6) + (fk << 1));  // bytes
  const u32 bfrag = (u32)(((wn + fr) << 6) + (fk << 1));

  const int nk = K >> 5;  // >= 4

#define P128_ISSUE(t, bf)                                                        \
  do {                                                                           \
    const int k0_ = (t) << 5;                                                    \
    __builtin_amdgcn_global_load_lds((GAS const u32*)(gA0 + k0_),                \
                                     (LAS u32*)(As[bf] + aoff), 16, 0, 0);       \
    __builtin_amdgcn_global_load_lds((GAS const u32*)(gA1 + k0_),                \
                                     (LAS u32*)(As[bf] + aoff + 512), 16, 0, 0); \
    __builtin_amdgcn_global_load_lds((GAS const u32*)(gB0 + k0_),                \
                                     (LAS u32*)(Bs[bf] + aoff), 16, 0, 0);       \
    __builtin_amdgcn_global_load_lds((GAS const u32*)(gB1 + k0_),                \
                                     (LAS u32*)(Bs[bf] + aoff + 512), 16, 0, 0); \
  } while (0)

  P128_ISSUE(0, 0);
  P128_ISSUE(1, 1);
  P128_ISSUE(2, 2);

  auto compute = [&](int kt) __attribute__((always_inline)) {
    const u32 ab = asb + ((u32)(kt & 3) << 13) + afrag;  // buf stride 8 KB
    const u32 bb = bsb + ((u32)(kt & 3) << 13) + bfrag;
    v8s a0, a1, a2, a3, b0, b1, b2, b3;
    asm volatile("ds_read_b128 %0, %1 offset:0"    : "=v"(a0) : "v"(ab));
    asm volatile("ds_read_b128 %0, %1 offset:1024" : "=v"(a1) : "v"(ab));
    asm volatile("ds_read_b128 %0, %1 offset:2048" : "=v"(a2) : "v"(ab));
    asm volatile("ds_read_b128 %0, %1 offset:3072" : "=v"(a3) : "v"(ab));
    asm volatile("ds_read_b128 %0, %1 offset:0"    : "=v"(b0) : "v"(bb));
    asm volatile("ds_read_b128 %0, %1 offset:1024" : "=v"(b1) : "v"(bb));
    asm volatile("ds_read_b128 %0, %1 offset:2048" : "=v"(b2) : "v"(bb));
    asm volatile("ds_read_b128 %0, %1 offset:3072" : "=v"(b3) : "v"(bb));
    asm volatile("s_waitcnt lgkmcnt(0)"
                 : "+v"(a0), "+v"(a1), "+v"(a2), "+v"(a3),
                   "+v"(b0), "+v"(b1), "+v"(b2), "+v"(b3)
                 :
                 : "memory");
    acc[0][0] = __builtin_amdgcn_mfma_f32_16x16x32_bf16(a0, b0, acc[0][0], 0, 0, 0);
    acc[0][1] = __builtin_amdgcn_mfma_f32_16x16x32_bf16(a0, b1, acc[0][1], 0, 0, 0);
    acc[0][2] = __builtin_amdgcn_mfma_f32_16x16x32_bf16(a0, b2, acc[0][2], 0, 0, 0);
    acc[0][3] = __builtin_amdgcn_mfma_f32_16x16x32_bf16(a0, b3, acc[0][3], 0, 0, 0);
    acc[1][0] = __builtin_amdgcn_mfma_f32_16x16x32_bf16(a1, b0, acc[1][0], 0, 0, 0);
    acc[1][1] = __builtin_amdgcn_mfma_f32_16x16x32_bf16(a1, b1, acc[1][1], 0, 0, 0);
    acc[1][2] = __builtin_amdgcn_mfma_f32_16x16x32_bf16(a1, b2, acc[1][2], 0, 0, 0);
    acc[1][3] = __builtin_amdgcn_mfma_f32_16x16x32_bf16(a1, b3, acc[1][3], 0, 0, 0);
    acc[2][0] = __builtin_amdgcn_mfma_f32_16x16x32_bf16(a2, b0, acc[2][0], 0, 0, 0);
    acc[2][1] = __builtin_amdgcn_mfma_f32_16x16x32_bf16(a2, b1, acc[2][1], 0, 0, 0);
    acc[2][2] = __builtin_amdgcn_mfma_f32_16x16x32_bf16(a2, b2, acc[2][2], 0, 0, 0);
    acc[2][3] = __builtin_amdgcn_mfma_f32_16x16x32_bf16(a2, b3, acc[2][3], 0, 0, 0);
    acc[3][0] = __builtin_amdgcn_mfma_f32_16x16x32_bf16(a3, b0, acc[3][0], 0, 0, 0);
    acc[3][1] = __builtin_amdgcn_mfma_f32_16x16x32_bf16(a3, b1, acc[3][1], 0, 0, 0);
    acc[3][2] = __builtin_amdgcn_mfma_f32_16x16x32_bf16(a3, b2, acc[3][2], 0, 0, 0);
    acc[3][3] = __builtin_amdgcn_mfma_f32_16x16x32_bf16(a3, b3, acc[3][3], 0, 0, 0);
  };

  for (int kt = 0; kt < nk - 3; ++kt) {
    asm volatile("s_waitcnt vmcnt(8)" ::: "memory");
    __builtin_amdgcn_s_barrier();
    P128_ISSUE(kt + 3, (kt + 3) & 3);
    compute(kt);
  }
  asm volatile("s_waitcnt vmcnt(8)" ::: "memory");
  __builtin_amdgcn_s_barrier();
  compute(nk - 3);
  asm volatile("s_waitcnt vmcnt(4)" ::: "memory");
  __builtin_amdgcn_s_barrier();
  compute(nk - 2);
  asm volatile("s_waitcnt vmcnt(0)" ::: "memory");
  __builtin_amdgcn_s_barrier();
  compute(nk - 1);
#undef P128_ISSUE

  const int er = (lane >> 4) << 2;
#pragma unroll
  for (int mi = 0; mi < 4; ++mi) {
#pragma unroll
    for (int ni = 0; ni < 4; ++ni) {
      const int col = n0 + wn + ni * 16 + fr;
      const float bcol = bias[col];
#pragma unroll
      for (int r = 0; r < 4; ++r) {
        const int row = m0 + wm + mi * 16 + er + r;
        float v = acc[mi][ni][r] + bcol;
        if constexpr (EPI == 1) {
          const float t = fast_tanh(0.7978845608028654f * (v + 0.044715f * v * v * v));
          v = 0.5f * v * (1.f + t);
        }
        if constexpr (EPI == 2) {
          v += res[(size_t)row * N + col];
          ((float*)outp)[(size_t)row * N + col] = v;
        } else {
          ((u16*)outp)[(size_t)row * N + col] = f2bf(v);
        }
      }
    }
  }
}

// ------- GEMM 128x128, depth-5 / 6-buffer pipeline (fc2: 1 block/CU) -----
// 96 KB LDS. Steady state: 20 loads in flight, vmcnt(16) drains only the 4
// oldest (tile kt) -> prefetch lead = 5 compute phases > HBM latency.
template <int EPI>
__global__ __launch_bounds__(256)
void gemm_bt_p6(const u16* __restrict__ A, const u16* __restrict__ Bt,
                const float* __restrict__ bias, const float* __restrict__ res,
                void* __restrict__ outp, int M, int N, int K) {
  __shared__ u16 As[6][128 * 32];
  __shared__ u16 Bs[6][128 * 32];
  const int tid = threadIdx.x;
  const int wave = tid >> 6, lane = tid & 63;
  const int m0 = blockIdx.y << 7, n0 = blockIdx.x << 7;

  v4f acc[4][4];
  const v4f vz = {0.f, 0.f, 0.f, 0.f};
#pragma unroll
  for (int i = 0; i < 4; ++i)
#pragma unroll
    for (int j = 0; j < 4; ++j) acc[i][j] = vz;

  const int wm = (wave >> 1) << 6, wn = (wave & 1) << 6;
  const int sr = lane >> 2;
  const int sc = (lane & 3) << 3;
  const int fr = lane & 15;
  const int fk = (lane >> 4) << 3;
  const int c0 = wave << 1;

  const u16* gA0 = A + (size_t)(m0 + c0 * 16 + sr) * K + sc;
  const u16* gA1 = A + (size_t)(m0 + c0 * 16 + 16 + sr) * K + sc;
  const u16* gB0 = Bt + (size_t)(n0 + c0 * 16 + sr) * K + sc;
  const u16* gB1 = Bt + (size_t)(n0 + c0 * 16 + 16 + sr) * K + sc;
  const int aoff = c0 * 512;

  const u32 asb = (u32)(size_t)(LAS const u16*)&As[0][0];
  const u32 bsb = (u32)(size_t)(LAS const u16*)&Bs[0][0];
  const u32 afrag = (u32)(((wm + fr) << 6) + (fk << 1));
  const u32 bfrag = (u32)(((wn + fr) << 6) + (fk << 1));

  const int nk = K >> 5;  // >= 6 (fc2: 128)

#define P6_ISSUE(t, bf)                                                          \
  do {                                                                           \
    const int k0_ = (t) << 5;                                                    \
    __builtin_amdgcn_global_load_lds((GAS const u32*)(gA0 + k0_),                \
                                     (LAS u32*)(As[bf] + aoff), 16, 0, 0);       \
    __builtin_amdgcn_global_load_lds((GAS const u32*)(gA1 + k0_),                \
                                     (LAS u32*)(As[bf] + aoff + 512), 16, 0, 0); \
    __builtin_amdgcn_global_load_lds((GAS const u32*)(gB0 + k0_),                \
                                     (LAS u32*)(Bs[bf] + aoff), 16, 0, 0);       \
    __builtin_amdgcn_global_load_lds((GAS const u32*)(gB1 + k0_),                \
                                     (LAS u32*)(Bs[bf] + aoff + 512), 16, 0, 0); \
  } while (0)

  P6_ISSUE(0, 0);
  P6_ISSUE(1, 1);
  P6_ISSUE(2, 2);
  P6_ISSUE(3, 3);
  P6_ISSUE(4, 4);

  auto compute = [&](int cbuf) __attribute__((always_inline)) {
    const u32 ab = asb + ((u32)cbuf << 13) + afrag;  // buf stride 8 KB
    const u32 bb = bsb + ((u32)cbuf << 13) + bfrag;
    v8s a0, a1, a2, a3, b0, b1, b2, b3;
    asm volatile("ds_read_b128 %0, %1 offset:0"    : "=v"(a0) : "v"(ab));
    asm volatile("ds_read_b128 %0, %1 offset:1024" : "=v"(a1) : "v"(ab));
    asm volatile("ds_read_b128 %0, %1 offset:2048" : "=v"(a2) : "v"(ab));
    asm volatile("ds_read_b128 %0, %1 offset:3072" : "=v"(a3) : "v"(ab));
    asm volatile("ds_read_b128 %0, %1 offset:0"    : "=v"(b0) : "v"(bb));
    asm volatile("ds_read_b128 %0, %1 offset:1024" : "=v"(b1) : "v"(bb));
    asm volatile("ds_read_b128 %0, %1 offset:2048" : "=v"(b2) : "v"(bb));
    asm volatile("ds_read_b128 %0, %1 offset:3072" : "=v"(b3) : "v"(bb));
    asm volatile("s_waitcnt lgkmcnt(0)"
                 : "+v"(a0), "+v"(a1), "+v"(a2), "+v"(a3),
                   "+v"(b0), "+v"(b1), "+v"(b2), "+v"(b3)
                 :
                 : "memory");
    acc[0][0] = __builtin_amdgcn_mfma_f32_16x16x32_bf16(a0, b0, acc[0][0], 0, 0, 0);
    acc[0][1] = __builtin_amdgcn_mfma_f32_16x16x32_bf16(a0, b1, acc[0][1], 0, 0, 0);
    acc[0][2] = __builtin_amdgcn_mfma_f32_16x16x32_bf16(a0, b2, acc[0][2], 0, 0, 0);
    acc[0][3] = __builtin_amdgcn_mfma_f32_16x16x32_bf16(a0, b3, acc[0][3], 0, 0, 0);
    acc[1][0] = __builtin_amdgcn_mfma_f32_16x16x32_bf16(a1, b0, acc[1][0], 0, 0, 0);
    acc[1][1] = __builtin_amdgcn_mfma_f32_16x16x32_bf16(a1, b1, acc[1][1], 0, 0, 0);
    acc[1][2] = __builtin_amdgcn_mfma_f32_16x16x32_bf16(a1, b2, acc[1][2], 0, 0, 0);
    acc[1][3] = __builtin_amdgcn_mfma_f32_16x16x32_bf16(a1, b3, acc[1][3], 0, 0, 0);
    acc[2][0] = __builtin_amdgcn_mfma_f32_16x16x32_bf16(a2, b0, acc[2][0], 0, 0, 0);
    acc[2][1] = __builtin_amdgcn_mfma_f32_16x16x32_bf16(a2, b1, acc[2][1], 0, 0, 0);
    acc[2][2] = __builtin_amdgcn_mfma_f32_16x16x32_bf16(a2, b2, acc[2][2], 0, 0, 0);
    acc[2][3] = __builtin_amdgcn_mfma_f32_16x16x32_bf16(a2, b3, acc[2][3], 0, 0, 0);
    acc[3][0] = __builtin_amdgcn_mfma_f32_16x16x32_bf16(a3, b0, acc[3][0], 0, 0, 0);
    acc[3][1] = __builtin_amdgcn_mfma_f32_16x16x32_bf16(a3, b1, acc[3][1], 0, 0, 0);
    acc[3][2] = __builtin_amdgcn_mfma_f32_16x16x32_bf16(a3, b2, acc[3][2], 0, 0, 0);
    acc[3][3] = __builtin_amdgcn_mfma_f32_16x16x32_bf16(a3, b3, acc[3][3], 0, 0, 0);
  };

  int cb = 0;       // buffer of tile kt
  int pb = 5;       // buffer of tile kt+5
  for (int kt = 0; kt < nk - 5; ++kt) {
    asm volatile("s_waitcnt vmcnt(16)" ::: "memory");
    __builtin_amdgcn_s_barrier();
    P6_ISSUE(kt + 5, pb);
    compute(cb);
    cb = (cb == 5) ? 0 : cb + 1;
    pb = (pb == 5) ? 0 : pb + 1;
  }
  asm volatile("s_waitcnt vmcnt(16)" ::: "memory");
  __builtin_amdgcn_s_barrier();
  compute(cb); cb = (cb == 5) ? 0 : cb + 1;
  asm volatile("s_waitcnt vmcnt(12)" ::: "memory");
  __builtin_amdgcn_s_barrier();
  compute(cb); cb = (cb == 5) ? 0 : cb + 1;
  asm volatile("s_waitcnt vmcnt(8)" ::: "memory");
  __builtin_amdgcn_s_barrier();
  compute(cb); cb = (cb == 5) ? 0 : cb + 1;
  asm volatile("s_waitcnt vmcnt(4)" ::: "memory");
  __builtin_amdgcn_s_barrier();
  compute(cb); cb = (cb == 5) ? 0 : cb + 1;
  asm volatile("s_waitcnt vmcnt(0)" ::: "memory");
  __builtin_amdgcn_s_barrier();
  compute(cb);
#undef P6_ISSUE

  const int er = (lane >> 4) << 2;
#pragma unroll
  for (int mi = 0; mi < 4; ++mi) {
#pragma unroll
    for (int ni = 0; ni < 4; ++ni) {
      const int col = n0 + wn + ni * 16 + fr;
      const float bcol = bias[col];
#pragma unroll
      for (int r = 0; r < 4; ++r) {
        const int row = m0 + wm + mi * 16 + er + r;
        float v = acc[mi][ni][r] + bcol;
        if constexpr (EPI == 1) {
          const float t = fast_tanh(0.7978845608028654f * (v + 0.044715f * v * v * v));
          v = 0.5f * v * (1.f + t);
        }
        if constexpr (EPI == 2) {
          v += res[(size_t)row * N + col];
          ((float*)outp)[(size_t)row * N + col] = v;
        } else {
          ((u16*)outp)[(size_t)row * N + col] = f2bf(v);
        }
      }
    }
  }
}

// ------- GEMM 128x64, depth-3 prefetch, asm ds_read (proj) ---------------
template <int EPI>
__global__ __launch_bounds__(256)
void gemm_bt_n64(const u16* __restrict__ A, const u16* __restrict__ Bt,
                 const float* __restrict__ bias, const float* __restrict__ res,
                 void* __restrict__ outp, int M, int N, int K) {
  __shared__ u16 As[4][128 * 32];
  __shared__ u16 Bs[4][64 * 32];
  const int tid = threadIdx.x;
  const int wave = tid >> 6, lane = tid & 63;
  const int m0 = blockIdx.y << 7, n0 = blockIdx.x << 6;

  v4f acc[4][2];
  const v4f vz = {0.f, 0.f, 0.f, 0.f};
#pragma unroll
  for (int i = 0; i < 4; ++i)
#pragma unroll
    for (int j = 0; j < 2; ++j) acc[i][j] = vz;

  const int wm = (wave >> 1) << 6, wn = (wave & 1) << 5;
  const int sr = lane >> 2;
  const int sc = (lane & 3) << 3;
  const int fr = lane & 15;
  const int fk = (lane >> 4) << 3;

  const u16* gA0 = A + (size_t)(m0 + wave * 32 + sr) * K + sc;
  const u16* gA1 = A + (size_t)(m0 + wave * 32 + 16 + sr) * K + sc;
  const u16* gB0 = Bt + (size_t)(n0 + wave * 16 + sr) * K + sc;
  const int aoff = wave * 1024;
  const int boff = wave * 512;

  const u32 asb = (u32)(size_t)(LAS const u16*)&As[0][0];
  const u32 bsb = (u32)(size_t)(LAS const u16*)&Bs[0][0];
  const u32 afrag = (u32)(((wm + fr) << 6) + (fk << 1));
  const u32 bfrag = (u32)(((wn + fr) << 6) + (fk << 1));

  const int nk = K >> 5;

#define N64_ISSUE(t, bf)                                                      \
  do {                                                                        \
    const int k0_ = (t) << 5;                                                 \
    __builtin_amdgcn_global_load_lds((GAS const u32*)(gA0 + k0_),             \
                                     (LAS u32*)(As[bf] + aoff), 16, 0, 0);    \
    __builtin_amdgcn_global_load_lds((GAS const u32*)(gA1 + k0_),             \
                                     (LAS u32*)(As[bf] + aoff + 512), 16, 0, 0); \
    __builtin_amdgcn_global_load_lds((GAS const u32*)(gB0 + k0_),             \
                                     (LAS u32*)(Bs[bf] + boff), 16, 0, 0);    \
  } while (0)

  N64_ISSUE(0, 0);
  N64_ISSUE(1, 1);
  N64_ISSUE(2, 2);

  auto compute = [&](int kt) __attribute__((always_inline)) {
    const u32 ab = asb + ((u32)(kt & 3) << 13) + afrag;  // A buf stride 8 KB
    const u32 bb = bsb + ((u32)(kt & 3) << 12) + bfrag;  // B buf stride 4 KB
    v8s a0, a1, a2, a3, b0, b1;
    asm volatile("ds_read_b128 %0, %1 offset:0"    : "=v"(a0) : "v"(ab));
    asm volatile("ds_read_b128 %0, %1 offset:1024" : "=v"(a1) : "v"(ab));
    asm volatile("ds_read_b128 %0, %1 offset:2048" : "=v"(a2) : "v"(ab));
    asm volatile("ds_read_b128 %0, %1 offset:3072" : "=v"(a3) : "v"(ab));
    asm volatile("ds_read_b128 %0, %1 offset:0"    : "=v"(b0) : "v"(bb));
    asm volatile("ds_read_b128 %0, %1 offset:1024" : "=v"(b1) : "v"(bb));
    asm volatile("s_waitcnt lgkmcnt(0)"
                 : "+v"(a0), "+v"(a1), "+v"(a2), "+v"(a3), "+v"(b0), "+v"(b1)
                 :
                 : "memory");
    acc[0][0] = __builtin_amdgcn_mfma_f32_16x16x32_bf16(a0, b0, acc[0][0], 0, 0, 0);
    acc[0][1] = __builtin_amdgcn_mfma_f32_16x16x32_bf16(a0, b1, acc[0][1], 0, 0, 0);
    acc[1][0] = __builtin_amdgcn_mfma_f32_16x16x32_bf16(a1, b0, acc[1][0], 0, 0, 0);
    acc[1][1] = __builtin_amdgcn_mfma_f32_16x16x32_bf16(a1, b1, acc[1][1], 0, 0, 0);
    acc[2][0] = __builtin_amdgcn_mfma_f32_16x16x32_bf16(a2, b0, acc[2][0], 0, 0, 0);
    acc[2][1] = __builtin_amdgcn_mfma_f32_16x16x32_bf16(a2, b1, acc[2][1], 0, 0, 0);
    acc[3][0] = __builtin_amdgcn_mfma_f32_16x16x32_bf16(a3, b0, acc[3][0], 0, 0, 0);
    acc[3][1] = __builtin_amdgcn_mfma_f32_16x16x32_bf16(a3, b1, acc[3][1], 0, 0, 0);
  };

  for (int kt = 0; kt < nk - 2; ++kt) {
    asm volatile("s_waitcnt vmcnt(6)" ::: "memory");
    __builtin_amdgcn_s_barrier();
    if (kt + 3 < nk) N64_ISSUE(kt + 3, (kt + 3) & 3);
    compute(kt);
  }
  asm volatile("s_waitcnt vmcnt(3)" ::: "memory");
  __builtin_amdgcn_s_barrier();
  compute(nk - 2);
  asm volatile("s_waitcnt vmcnt(0)" ::: "memory");
  __builtin_amdgcn_s_barrier();
  compute(nk - 1);
#undef N64_ISSUE

  const int er = (lane >> 4) << 2;
#pragma unroll
  for (int mi = 0; mi < 4; ++mi) {
#pragma unroll
    for (int ni = 0; ni < 2; ++ni) {
      const int col = n0 + wn + ni * 16 + fr;
      const float bcol = bias[col];
#pragma unroll
      for (int r = 0; r < 4; ++r) {
        const int row = m0 + wm + mi * 16 + er + r;
        float v = acc[mi][ni][r] + bcol;
        if constexpr (EPI == 1) {
          const float t = fast_tanh(0.7978845608028654f * (v + 0.044715f * v * v * v));
          v = 0.5f * v * (1.f + t);
        }
        if constexpr (EPI == 2) {
          v += res[(size_t)row * N + col];
          ((float*)outp)[(size_t)row * N + col] = v;
        } else {
          ((u16*)outp)[(size_t)row * N + col] = f2bf(v);
        }
      }
    }
  }
}

// ---------------- V -> Vt [B,H,D,T] bf16 (transpose via LDS) -------------
__global__ __launch_bounds__(256)
void transpose_v(const u16* __restrict__ qkv, u16* __restrict__ Vt) {
  __shared__ u16 tile[64][65];
  const int t0 = blockIdx.x << 6;
  const int bh = blockIdx.y;
  const int b = bh >> 4, h = bh & 15;
  const int r4 = threadIdx.x >> 6, c = threadIdx.x & 63;
#pragma unroll
  for (int i = 0; i < 16; ++i) {
    const int r = r4 * 16 + i;
    tile[r][c] = qkv[(size_t)(b * 2048 + t0 + r) * 3072 + 2048 + h * 64 + c];
  }
  __syncthreads();
#pragma unroll
  for (int i = 0; i < 16; ++i) {
    const int d = r4 * 16 + i;
    Vt[(size_t)bh * 64 * 2048 + (size_t)d * 2048 + t0 + c] = tile[c][d];
  }
}

// ---------------- flash attention (causal, balanced pairing) -------------
constexpr int PSTR = 88;  // P row stride (u16): 176B = 16B-mult, 2-way banks

template <bool MASKED>
__device__ __forceinline__ void attn_sub(
    const v8s (&kf)[4][2], const v8s (&vfr)[4][2], const v8s (&qf)[2],
    v4f (&ot)[4], float& m_i, float& l_i, u16* __restrict__ pw,
    const int kb, const int qrow, const int fr, const int fg) {
  const v4f vz = {0.f, 0.f, 0.f, 0.f};
  v4f st[4];
#pragma unroll
  for (int ks = 0; ks < 4; ++ks) {
    st[ks] = vz;
    st[ks] = __builtin_amdgcn_mfma_f32_16x16x32_bf16(kf[ks][0], qf[0], st[ks], 0, 0, 0);
    st[ks] = __builtin_amdgcn_mfma_f32_16x16x32_bf16(kf[ks][1], qf[1], st[ks], 0, 0, 0);
  }
  const int q = qrow + fr;
  float e[4][4];
  float mt = -1e30f;
#pragma unroll
  for (int ks = 0; ks < 4; ++ks)
#pragma unroll
    for (int r = 0; r < 4; ++r) {
      float v = st[ks][r] * 0.125f;  // fold 1/sqrt(64)
      if (MASKED) v = (kb + ks * 16 + fg * 4 + r <= q) ? v : -1e30f;
      e[ks][r] = v;
      mt = fmaxf(mt, v);
    }
  mt = fmaxf(mt, __shfl_xor(mt, 16));
  mt = fmaxf(mt, __shfl_xor(mt, 32));
  const float m_new = fmaxf(m_i, mt);
  const float alpha = __expf(m_i - m_new);
  m_i = m_new;
  float ls = 0.f;
#pragma unroll
  for (int ks = 0; ks < 4; ++ks)
#pragma unroll
    for (int r = 0; r < 4; ++r) {
      e[ks][r] = __expf(e[ks][r] - m_new);
      ls += e[ks][r];
    }
  ls += __shfl_xor(ls, 16);
  ls += __shfl_xor(ls, 32);
  l_i = l_i * alpha + ls;
#pragma unroll
  for (int ds = 0; ds < 4; ++ds) ot[ds] *= alpha;
#pragma unroll
  for (int ks = 0; ks < 4; ++ks) {
    ushort4 pk4;
    pk4.x = f2bf(e[ks][0]);
    pk4.y = f2bf(e[ks][1]);
    pk4.z = f2bf(e[ks][2]);
    pk4.w = f2bf(e[ks][3]);
    *(ushort4*)&pw[fr * PSTR + ks * 16 + fg * 4] = pk4;
  }
  const v8s pf0 = *(const v8s*)&pw[fr * PSTR + fg * 8];
  const v8s pf1 = *(const v8s*)&pw[fr * PSTR + 32 + fg * 8];
#pragma unroll
  for (int ds = 0; ds < 4; ++ds) {
    ot[ds] = __builtin_amdgcn_mfma_f32_16x16x32_bf16(vfr[ds][0], pf0, ot[ds], 0, 0, 0);
    ot[ds] = __builtin_amdgcn_mfma_f32_16x16x32_bf16(vfr[ds][1], pf1, ot[ds], 0, 0, 0);
  }
}

__global__ __launch_bounds__(256)
void attn_kernel(const u16* __restrict__ qkv, const u16* __restrict__ Vt,
                 u16* __restrict__ y) {
  constexpr int T = 2048, D = 64, C = 1024, QS = 3072;
  __shared__ alignas(16) u16 Ktile[2][64 * 64];
  __shared__ alignas(16) u16 Vtile[2][64 * 64];
  __shared__ alignas(16) u16 Pw[4][16 * PSTR];

  const int tid = threadIdx.x, wave = tid >> 6, lane = tid & 63;
  const int fr = lane & 15, fg = lane >> 4;
  const int bh = blockIdx.y, b = bh >> 4, h = bh & 15;
  const int ta = blockIdx.x, tb = 31 - ta;
  const u16* qkvb = qkv + (size_t)b * T * QS + h * 64;  // Q base
  const u16* Kg = qkvb + 1024;                          // K base
  const u16* Vh = Vt + (size_t)bh * D * T;
  u16* pw = &Pw[wave][0];

  const int rowA = ta * 64 + wave * 16;
  const int rowB = tb * 64 + wave * 16;

  v8s qfA[2], qfB[2];
#pragma unroll
  for (int dh = 0; dh < 2; ++dh) {
    qfA[dh] = *(const v8s*)&qkvb[(size_t)(rowA + fr) * QS + dh * 32 + fg * 8];
    qfB[dh] = *(const v8s*)&qkvb[(size_t)(rowB + fr) * QS + dh * 32 + fg * 8];
  }

  const v4f vz = {0.f, 0.f, 0.f, 0.f};
  v4f otA[4], otB[4];
#pragma unroll
  for (int ds = 0; ds < 4; ++ds) { otA[ds] = vz; otB[ds] = vz; }
  float mA = -1e30f, lA = 0.f, mB = -1e30f, lB = 0.f;

  const int srow = lane >> 3;
  const int sg0 = lane & 7;

  const int nt = tb + 1;
  {
#pragma unroll
    for (int cc = 0; cc < 2; ++cc) {
      const int r0 = wave * 16 + cc * 8;
      const int rr = r0 + srow;
      const int gg = sg0 ^ (rr & 7);
      __builtin_amdgcn_global_load_lds(
          (GAS const u32*)(Kg + (size_t)rr * QS + gg * 8),
          (LAS u32*)(Ktile[0] + r0 * 64), 16, 0, 0);
      __builtin_amdgcn_global_load_lds(
          (GAS const u32*)(Vh + (size_t)rr * T + gg * 8),
          (LAS u32*)(Vtile[0] + r0 * 64), 16, 0, 0);
    }
  }
  for (int kt = 0; kt < nt; ++kt) {
    __syncthreads();
    if (kt + 1 < nt) {
      const int kb1 = (kt + 1) << 6;
      const int nb = (kt + 1) & 1;
#pragma unroll
      for (int cc = 0; cc < 2; ++cc) {
        const int r0 = wave * 16 + cc * 8;
        const int rr = r0 + srow;
        const int gg = sg0 ^ (rr & 7);
        __builtin_amdgcn_global_load_lds(
            (GAS const u32*)(Kg + (size_t)(kb1 + rr) * QS + gg * 8),
            (LAS u32*)(Ktile[nb] + r0 * 64), 16, 0, 0);
        __builtin_amdgcn_global_load_lds(
            (GAS const u32*)(Vh + (size_t)rr * T + kb1 + gg * 8),
            (LAS u32*)(Vtile[nb] + r0 * 64), 16, 0, 0);
      }
    }
    const u16* Kt = Ktile[kt & 1];
    const u16* Vi = Vtile[kt & 1];
    const int kb = kt << 6;
    const int swz = fr & 7;
    v8s kf[4][2], vfr[4][2];
#pragma unroll
    for (int ks = 0; ks < 4; ++ks) {
      const int rr = ks * 16 + fr;
      kf[ks][0] = *(const v8s*)&Kt[rr * 64 + ((0 + fg) ^ swz) * 8];
      kf[ks][1] = *(const v8s*)&Kt[rr * 64 + ((4 + fg) ^ swz) * 8];
      vfr[ks][0] = *(const v8s*)&Vi[rr * 64 + ((0 + fg) ^ swz) * 8];
      vfr[ks][1] = *(const v8s*)&Vi[rr * 64 + ((4 + fg) ^ swz) * 8];
    }
    if (kt < ta) {
      attn_sub<false>(kf, vfr, qfA, otA, mA, lA, pw, kb, rowA, fr, fg);
      attn_sub<false>(kf, vfr, qfB, otB, mB, lB, pw, kb, rowB, fr, fg);
    } else if (kt == ta) {
      attn_sub<true>(kf, vfr, qfA, otA, mA, lA, pw, kb, rowA, fr, fg);
      attn_sub<false>(kf, vfr, qfB, otB, mB, lB, pw, kb, rowB, fr, fg);
    } else if (kt < tb) {
      attn_sub<false>(kf, vfr, qfB, otB, mB, lB, pw, kb, rowB, fr, fg);
    } else {
      attn_sub<true>(kf, vfr, qfB, otB, mB, lB, pw, kb, rowB, fr, fg);
    }
  }

  const float invA = 1.f / lA, invB = 1.f / lB;
#pragma unroll
  for (int ds = 0; ds < 4; ++ds) {
    ushort4 a4, b4;
    a4.x = f2bf(otA[ds][0] * invA);
    a4.y = f2bf(otA[ds][1] * invA);
    a4.z = f2bf(otA[ds][2] * invA);
    a4.w = f2bf(otA[ds][3] * invA);
    b4.x = f2bf(otB[ds][0] * invB);
    b4.y = f2bf(otB[ds][1] * invB);
    b4.z = f2bf(otB[ds][2] * invB);
    b4.w = f2bf(otB[ds][3] * invB);
    *(ushort4*)&y[(size_t)(b * T + rowA + fr) * C + h * D + ds * 16 + fg * 4] = a4;
    *(ushort4*)&y[(size_t)(b * T + rowB + fr) * C + h * D + ds * 16 + fg * 4] = b4;
  }
}

// ------------------------------- launch ----------------------------------
extern "C" void kernel_launch(void* const* d_in, const int* in_sizes, int n_in,
                              void* d_out, int out_size, void* d_ws, size_t ws_size,
                              hipStream_t stream) {
  const float* x      = (const float*)d_in[0];
  const float* ln1_g  = (const float*)d_in[1];
  const float* ln1_b  = (const float*)d_in[2];
  const float* W_attn = (const float*)d_in[3];
  const float* b_attn = (const float*)d_in[4];
  const float* W_o    = (const float*)d_in[5];
  const float* b_o    = (const float*)d_in[6];
  const float* ln2_g  = (const float*)d_in[7];
  const float* ln2_b  = (const float*)d_in[8];
  const float* W_fc   = (const float*)d_in[9];
  const float* b_fc   = (const float*)d_in[10];
  const float* W_fc2  = (const float*)d_in[11];
  const float* b_fc2  = (const float*)d_in[12];
  float* out = (float*)d_out;
  char* ws = (char*)d_ws;

  const size_t MB = 1u << 20;
  u16* Wattn_t = (u16*)(ws + 0 * MB);   // 6MB
  u16* Wo_t    = (u16*)(ws + 6 * MB);   // 2MB
  u16* Wfc_t   = (u16*)(ws + 8 * MB);   // 8MB
  u16* Wfc2_t  = (u16*)(ws + 16 * MB);  // 8MB
  float* x1    = (float*)(ws + 24 * MB); // 16MB
  u16* h1      = (u16*)(ws + 40 * MB);  // 8MB
  u16* qkv     = (u16*)(ws + 48 * MB);  // 24MB (alive through attn)
  u16* Vt      = (u16*)(ws + 88 * MB);  // 8MB
  u16* yb      = (u16*)(ws + 40 * MB);  // reuse h1 (dead after qkv GEMM)
  u16* h2      = (u16*)(ws + 48 * MB);  // reuse qkv (dead after attn)
  u16* ab      = (u16*)(ws + 56 * MB);  // 32MB (56..88)

  wtrans<<<dim3(3072 / 32, 1024 / 32), 256, 0, stream>>>(W_attn, Wattn_t, 1024, 3072);
  wtrans<<<dim3(1024 / 32, 1024 / 32), 256, 0, stream>>>(W_o, Wo_t, 1024, 1024);
  wtrans<<<dim3(4096 / 32, 1024 / 32), 256, 0, stream>>>(W_fc, Wfc_t, 1024, 4096);
  wtrans<<<dim3(1024 / 32, 4096 / 32), 256, 0, stream>>>(W_fc2, Wfc2_t, 4096, 1024);

  ln_bf16<<<4096, 256, 0, stream>>>(x, ln1_g, ln1_b, h1);
  gemm_bt_p<0><<<dim3(3072 / 128, 4096 / 128), 256, 0, stream>>>(
      h1, Wattn_t, b_attn, nullptr, qkv, 4096, 3072, 1024);
  transpose_v<<<dim3(2048 / 64, 32), 256, 0, stream>>>(qkv, Vt);
  attn_kernel<<<dim3(16, 32), 256, 0, stream>>>(qkv, Vt, yb);
  gemm_bt_n64<2><<<dim3(1024 / 64, 4096 / 128), 256, 0, stream>>>(
      yb, Wo_t, b_o, x, x1, 4096, 1024, 1024);
  ln_bf16<<<4096, 256, 0, stream>>>(x1, ln2_g, ln2_b, h2);
  gemm_bt_p<1><<<dim3(4096 / 128, 4096 / 128), 256, 0, stream>>>(
      h2, Wfc_t, b_fc, nullptr, ab, 4096, 4096, 1024);
  gemm_bt_p6<2><<<dim3(1024 / 128, 4096 / 128), 256, 0, stream>>>(
      ab, Wfc2_t, b_fc2, x1, out, 4096, 1024, 4096);
}